// Round 5
// baseline (191.570 us; speedup 1.0000x reference)
//
#include <hip/hip_runtime.h>
#include <hip/hip_bf16.h>
#include <math.h>

#define B_DIM 8
#define T_DIM 2048
#define D_DIM 1024
#define H_DIM 64
#define SCALE 0.125f

typedef __attribute__((ext_vector_type(8))) short bf16x8;
typedef __attribute__((ext_vector_type(4))) float f32x4;

__device__ __forceinline__ f32x4 mfma16(bf16x8 a, bf16x8 b, f32x4 c) {
    return __builtin_amdgcn_mfma_f32_16x16x32_bf16(a, b, c, 0, 0, 0);
}

__device__ __forceinline__ float rcp_fast(float x) {
    float r;
    asm volatile("v_rcp_f32 %0, %1" : "=v"(r) : "v"(x));
    return r;
}

__device__ __forceinline__ short f2bf(float f) {
    __hip_bfloat16 h = __float2bfloat16(f);
    return *reinterpret_cast<short*>(&h);
}

__device__ __forceinline__ void cvt4(float4 v, short* dst) {
    __hip_bfloat162 p0 = __float22bfloat162_rn(make_float2(v.x, v.y));
    __hip_bfloat162 p1 = __float22bfloat162_rn(make_float2(v.z, v.w));
    uint2 u;
    u.x = *reinterpret_cast<unsigned int*>(&p0);
    u.y = *reinterpret_cast<unsigned int*>(&p1);
    *reinterpret_cast<uint2*>(dst) = u;  // dst 8B-aligned
}

// ---------------------------------------------------------------------------
// prep: transpose-convert W (fp32 [k][h]) -> wt bf16 [m][h][k]. 48 blocks.
// ---------------------------------------------------------------------------
__global__ __launch_bounds__(256) void prep_kernel(
    const float* __restrict__ Wq, const float* __restrict__ Wk,
    const float* __restrict__ Wv, short* __restrict__ wt)
{
    const int blk = blockIdx.x;
    const int tid = threadIdx.x;
    const int m = blk >> 4;
    const int ks = (blk & 15) << 6;
    const float* W = (m == 0) ? Wq : (m == 1) ? Wk : Wv;
    __shared__ float tile[64][68];
#pragma unroll
    for (int t = 0; t < 4; t++) {
        int fi = tid + t * 256;
        int k = fi >> 4, h4 = (fi & 15) << 2;
        *(float4*)&tile[k][h4] = *(const float4*)&W[(size_t)(ks + k) * H_DIM + h4];
    }
    __syncthreads();
    const int h = tid >> 2, seg = (tid & 3) << 4;
    __align__(16) short tmp[16];
#pragma unroll
    for (int kk = 0; kk < 16; kk++) tmp[kk] = f2bf(tile[seg + kk][h]);
    short* dst = wt + ((size_t)m * H_DIM + h) * D_DIM + ks + seg;
    *(bf16x8*)dst = *(bf16x8*)tmp;
    *(bf16x8*)(dst + 8) = *(bf16x8*)(tmp + 8);
}

// ---------------------------------------------------------------------------
// proj: grid 512 (32 rows each), block 256. q|k|v (192 cols) per row tile,
// double-buffered LDS (1 barrier/iter) + global->reg prefetch.
// Outputs: qb,kb bf16 [t][h]; vt bf16 [b][h][t].
// ---------------------------------------------------------------------------
__global__ __launch_bounds__(256) void proj_kernel(
    const float* __restrict__ x, const short* __restrict__ wt,
    short* __restrict__ qb, short* __restrict__ kb, short* __restrict__ vt)
{
    __shared__ short xs[2][32][72];
    __shared__ short wsb[2][192][72];
    __shared__ short ot[32][200];

    const int tid = threadIdx.x;
    const int wv = tid >> 6;
    const int lane = tid & 63;
    const int l15 = lane & 15;
    const int quad = lane >> 4;
    const int t0 = blockIdx.x * 32;
    const int r0 = (wv & 1) * 16;
    const int c0 = (wv >> 1) * 96;

    f32x4 acc[6];
#pragma unroll
    for (int c = 0; c < 6; c++) acc[c] = (f32x4){0.f, 0.f, 0.f, 0.f};

    float4 xr[2];
    bf16x8 wr[6];
    auto load_tile = [&](int k0) {
#pragma unroll
        for (int t = 0; t < 2; t++) {
            int fi = tid + t * 256;
            int r = fi >> 4, c4 = (fi & 15) << 2;
            xr[t] = *(const float4*)&x[(size_t)(t0 + r) * D_DIM + k0 + c4];
        }
#pragma unroll
        for (int t = 0; t < 6; t++) {
            int fi = tid + t * 256;
            int hh = fi >> 3, sg = (fi & 7) << 3;
            wr[t] = *(const bf16x8*)&wt[(size_t)hh * D_DIM + k0 + sg];
        }
    };
    auto store_tile = [&](int buf) {
#pragma unroll
        for (int t = 0; t < 2; t++) {
            int fi = tid + t * 256;
            int r = fi >> 4, c4 = (fi & 15) << 2;
            cvt4(xr[t], &xs[buf][r][c4]);
        }
#pragma unroll
        for (int t = 0; t < 6; t++) {
            int fi = tid + t * 256;
            int hh = fi >> 3, sg = (fi & 7) << 3;
            *(bf16x8*)&wsb[buf][hh][sg] = wr[t];
        }
    };

    load_tile(0);
    store_tile(0);
    __syncthreads();

    for (int it = 0; it < 16; ++it) {
        const int cur = it & 1;
        if (it < 15) load_tile((it + 1) * 64);
#pragma unroll
        for (int ks = 0; ks < 2; ks++) {
            bf16x8 xa = *(const bf16x8*)&xs[cur][r0 + l15][ks * 32 + quad * 8];
#pragma unroll
            for (int ct = 0; ct < 6; ct++) {
                bf16x8 wb = *(const bf16x8*)&wsb[cur][c0 + ct * 16 + l15][ks * 32 + quad * 8];
                acc[ct] = mfma16(xa, wb, acc[ct]);
            }
        }
        if (it < 15) store_tile(cur ^ 1);
        __syncthreads();
    }

    // epilogue: C-frags -> LDS bf16 tile
#pragma unroll
    for (int ct = 0; ct < 6; ct++)
#pragma unroll
        for (int r = 0; r < 4; r++)
            ot[r0 + quad * 4 + r][c0 + ct * 16 + l15] = f2bf(acc[ct][r]);
    __syncthreads();
#pragma unroll
    for (int t = 0; t < 2; t++) {
        int fi = tid + t * 256;
        int row = fi >> 4, sg = fi & 15;
        bf16x8 v = *(const bf16x8*)&ot[row][sg * 8];
        short* dst = (sg < 8)
            ? &qb[(size_t)(t0 + row) * H_DIM + sg * 8]
            : &kb[(size_t)(t0 + row) * H_DIM + (sg - 8) * 8];
        *(bf16x8*)dst = v;
    }
    {
        const int h = tid >> 2, ts = (tid & 3) << 3;
        const int bb = t0 >> 11;
        const int tloc = (t0 & 2047) + ts;
        __align__(16) short tmp[8];
#pragma unroll
        for (int i = 0; i < 8; i++) tmp[i] = ot[ts + i][128 + h];
        *(bf16x8*)&vt[((size_t)bb * H_DIM + h) * T_DIM + tloc] = *(bf16x8*)tmp;
    }
}

// ---------------------------------------------------------------------------
// stats: Z[k] = sum_{q>=k} exp(s*scale). grid (128, 8): block = one 16-col
// k-strip s (work = 128-s q-tiles, big strips dispatch first); 4 waves split
// the q-range. K stationary in regs, Q streamed w/ ping-pong prefetch.
// Butterfly + LDS reduce; one plain store per column.
// ---------------------------------------------------------------------------
__global__ __launch_bounds__(256) void stats_kernel(
    const short* __restrict__ qb, const short* __restrict__ kb,
    float* __restrict__ Zbuf)
{
    __shared__ float zred[4][16];
    const int tid = threadIdx.x;
    const int wv = tid >> 6;
    const int lane = tid & 63;
    const int l15 = lane & 15;
    const int quad = lane >> 4;
    const int b = blockIdx.y;
    const int s = blockIdx.x;        // k-strip 0..127; work = 128-s (big first)
    const int Ts = 128 - s;

    const short* qB_ = qb + (size_t)b * T_DIM * H_DIM;
    const short* kB_ = kb + (size_t)b * T_DIM * H_DIM;

    const short* kp = &kB_[(s * 16 + l15) * H_DIM + quad * 8];
    const bf16x8 a0 = *(const bf16x8*)kp;
    const bf16x8 a1 = *(const bf16x8*)(kp + 32);

    float acc[4] = {0.f, 0.f, 0.f, 0.f};

    const int lo = s + ((wv * Ts) >> 2);
    const int hi = s + (((wv + 1) * Ts) >> 2);

    bf16x8 qA0, qA1, qB0, qB1;
    auto loadQ = [&](int qt, bf16x8& r0, bf16x8& r1) {
        const short* qp = &qB_[(qt * 16 + l15) * H_DIM + quad * 8];
        r0 = *(const bf16x8*)qp;
        r1 = *(const bf16x8*)(qp + 32);
    };
    // result: row quad*4+r = k-col (A=K rows), col l15 = q (B=Q rows)
    auto comp = [&](int qt, bf16x8 b0, bf16x8 b1) {
        f32x4 sv = mfma16(a0, b0, (f32x4){0.f, 0.f, 0.f, 0.f});
        sv = mfma16(a1, b1, sv);
        const bool diag = (qt == s);
#pragma unroll
        for (int r = 0; r < 4; ++r) {
            float e = __expf(sv[r] * SCALE);
            if (diag && (quad * 4 + r) > l15) e = 0.f;   // mask k > q
            acc[r] += e;
        }
    };

    int v = lo;
    if (v < hi) loadQ(v, qA0, qA1);
    while (v < hi) {
        if (v + 1 < hi) loadQ(v + 1, qB0, qB1);
        comp(v, qA0, qA1);
        ++v;
        if (v >= hi) break;
        if (v + 1 < hi) loadQ(v + 1, qA0, qA1);
        comp(v, qB0, qB1);
        ++v;
    }

    // sum across q (l15 lanes) via butterfly, combine 4 waves in LDS
#pragma unroll
    for (int r = 0; r < 4; ++r) {
        float z = acc[r];
        z += __shfl_xor(z, 1);
        z += __shfl_xor(z, 2);
        z += __shfl_xor(z, 4);
        z += __shfl_xor(z, 8);
        acc[r] = z;
    }
    if (l15 == 0) {
#pragma unroll
        for (int r = 0; r < 4; ++r) zred[wv][quad * 4 + r] = acc[r];
    }
    __syncthreads();
    if (tid < 16) {
        float z = zred[0][tid] + zred[1][tid] + zred[2][tid] + zred[3][tid];
        Zbuf[(size_t)b * T_DIM + s * 16 + tid] = z;
    }
}

// ---------------------------------------------------------------------------
// out: grid (128, 8), block 256. Block = one 16-row q-strip (strip = 127-bx
// so the 64-tile strips dispatch first); waves quarter the k-range. Ping-pong
// register prefetch of K/V/Z. Partial O combined in LDS, coalesced stores.
// ---------------------------------------------------------------------------
__global__ __launch_bounds__(256) void out_kernel(
    const short* __restrict__ qb, const short* __restrict__ kb,
    const short* __restrict__ vt, const float* __restrict__ Zbuf,
    float* __restrict__ out)
{
    __shared__ float osum[4][16][68];      // 17.4 KB
    __shared__ short pbuf[4][16][40];      // per-wave P tile, 5 KB

    const int tid = threadIdx.x;
    const int wv = tid >> 6;
    const int lane = tid & 63;
    const int l15 = lane & 15;
    const int quad = lane >> 4;
    const int b = blockIdx.y;
    const int s = 127 - blockIdx.x;        // big strips first
    const int q0 = s * 16;
    const int Ts = (s >> 1) + 1;           // 32-col k-tiles in causal range
    const int lo = (wv * Ts) >> 2;
    const int hi = ((wv + 1) * Ts) >> 2;

    const short* qB_ = qb + (size_t)b * T_DIM * H_DIM;
    const short* kB_ = kb + (size_t)b * T_DIM * H_DIM;
    const short* vB_ = vt + (size_t)b * H_DIM * T_DIM;
    const float* zB_ = Zbuf + (size_t)b * T_DIM;
    short* pb = &pbuf[wv][0][0];

    const bf16x8 qa0 = *(const bf16x8*)&qB_[(q0 + l15) * H_DIM + quad * 8];
    const bf16x8 qa1 = *(const bf16x8*)&qB_[(q0 + l15) * H_DIM + 32 + quad * 8];

    f32x4 o0 = {0.f,0.f,0.f,0.f}, o1 = {0.f,0.f,0.f,0.f};
    f32x4 o2 = {0.f,0.f,0.f,0.f}, o3 = {0.f,0.f,0.f,0.f};

    bf16x8 krA[4], vrA[4], krB[4], vrB[4];
    float zA[2], zB2[2];

    auto loadT = [&](int kt, bf16x8* kr, bf16x8* vr, float* zz) {
        const short* kp = &kB_[(kt * 32 + l15) * H_DIM + quad * 8];
        kr[0] = *(const bf16x8*)kp;
        kr[1] = *(const bf16x8*)(kp + 32);
        kr[2] = *(const bf16x8*)(kp + 16 * H_DIM);
        kr[3] = *(const bf16x8*)(kp + 16 * H_DIM + 32);
        const short* vp = &vB_[(size_t)l15 * T_DIM + kt * 32 + quad * 8];
        vr[0] = *(const bf16x8*)vp;
        vr[1] = *(const bf16x8*)(vp + 16 * T_DIM);
        vr[2] = *(const bf16x8*)(vp + 32 * T_DIM);
        vr[3] = *(const bf16x8*)(vp + 48 * T_DIM);
        zz[0] = zB_[kt * 32 + l15];
        zz[1] = zB_[kt * 32 + 16 + l15];
    };
    auto compT = [&](int kt, bf16x8* kr, bf16x8* vr, float* zz) {
        f32x4 z4 = {0.f,0.f,0.f,0.f};
        f32x4 s0 = mfma16(qa0, kr[0], z4);
        s0 = mfma16(qa1, kr[1], s0);
        f32x4 s1 = mfma16(qa0, kr[2], z4);
        s1 = mfma16(qa1, kr[3], s1);
        const float zi0 = rcp_fast(zz[0]);
        const float zi1 = rcp_fast(zz[1]);
        const bool fullT = (kt * 32 + 31) <= q0;
        const int kg0 = kt * 32 + l15;
        const int kg1 = kg0 + 16;
#pragma unroll
        for (int r = 0; r < 4; r++) {
            int qg = q0 + quad * 4 + r;
            float e0 = __expf(s0[r] * SCALE) * zi0;
            float e1 = __expf(s1[r] * SCALE) * zi1;
            if (!fullT) {
                if (kg0 > qg) e0 = 0.f;
                if (kg1 > qg) e1 = 0.f;
            }
            pb[(quad * 4 + r) * 40 + l15] = f2bf(e0);
            pb[(quad * 4 + r) * 40 + 16 + l15] = f2bf(e1);
        }
        __asm__ volatile("s_waitcnt lgkmcnt(0)" ::: "memory");
        bf16x8 pa = *(const bf16x8*)&pb[l15 * 40 + quad * 8];
        o0 = mfma16(pa, vr[0], o0);
        o1 = mfma16(pa, vr[1], o1);
        o2 = mfma16(pa, vr[2], o2);
        o3 = mfma16(pa, vr[3], o3);
    };

    int kt = lo;
    if (kt < hi) loadT(kt, krA, vrA, zA);
    while (kt < hi) {
        if (kt + 1 < hi) loadT(kt + 1, krB, vrB, zB2);
        compT(kt, krA, vrA, zA);
        ++kt;
        if (kt >= hi) break;
        if (kt + 1 < hi) loadT(kt + 1, krA, vrA, zA);
        compT(kt, krB, vrB, zB2);
        ++kt;
    }

#pragma unroll
    for (int r = 0; r < 4; r++) {
        osum[wv][quad * 4 + r][l15]      = o0[r];
        osum[wv][quad * 4 + r][16 + l15] = o1[r];
        osum[wv][quad * 4 + r][32 + l15] = o2[r];
        osum[wv][quad * 4 + r][48 + l15] = o3[r];
    }
    __syncthreads();

    // combine 4 k-quarters, store 16 rows x 64 h
    const int row = tid >> 4;
    const int h0 = (tid & 15) * 4;
    float a[4];
#pragma unroll
    for (int i = 0; i < 4; i++)
        a[i] = osum[0][row][h0 + i] + osum[1][row][h0 + i] +
               osum[2][row][h0 + i] + osum[3][row][h0 + i];
    float* dst = &out[(size_t)(b * T_DIM + q0 + row) * H_DIM + h0];
    *(float4*)dst = make_float4(a[0], a[1], a[2], a[3]);
}

// ---------------------------------------------------------------------------
extern "C" void kernel_launch(void* const* d_in, const int* in_sizes, int n_in,
                              void* d_out, int out_size, void* d_ws, size_t ws_size,
                              hipStream_t stream) {
    const float* x  = (const float*)d_in[0];
    const float* Wk = (const float*)d_in[1];
    const float* Wq = (const float*)d_in[2];
    const float* Wv = (const float*)d_in[3];
    float* out = (float*)d_out;

    short* qbuf = (short*)d_ws;                       // 16384*64 bf16
    short* kbuf = qbuf + (size_t)16384 * 64;
    short* vtbuf = kbuf + (size_t)16384 * 64;         // [b][h][t]
    short* wtbuf = vtbuf + (size_t)16384 * 64;        // [3][64][1024]
    float* Zbuf = (float*)(wtbuf + (size_t)3 * 64 * 1024);  // [b][t]

    prep_kernel<<<48, 256, 0, stream>>>(Wq, Wk, Wv, wtbuf);
    proj_kernel<<<512, 256, 0, stream>>>(x, wtbuf, qbuf, kbuf, vtbuf);
    stats_kernel<<<dim3(128, B_DIM), 256, 0, stream>>>(qbuf, kbuf, Zbuf);
    out_kernel<<<dim3(128, B_DIM), 256, 0, stream>>>(qbuf, kbuf, vtbuf, Zbuf, out);
}

// Round 6
// 168.905 us; speedup vs baseline: 1.1342x; 1.1342x over previous
//
#include <hip/hip_runtime.h>
#include <hip/hip_bf16.h>
#include <math.h>

#define B_DIM 8
#define T_DIM 2048
#define D_DIM 1024
#define H_DIM 64
#define SCALE 0.125f

typedef __attribute__((ext_vector_type(8))) short bf16x8;
typedef __attribute__((ext_vector_type(4))) float f32x4;

__device__ __forceinline__ f32x4 mfma16(bf16x8 a, bf16x8 b, f32x4 c) {
    return __builtin_amdgcn_mfma_f32_16x16x32_bf16(a, b, c, 0, 0, 0);
}

__device__ __forceinline__ float rcp_fast(float x) {
    float r;
    asm volatile("v_rcp_f32 %0, %1" : "=v"(r) : "v"(x));
    return r;
}

__device__ __forceinline__ short f2bf(float f) {
    __hip_bfloat16 h = __float2bfloat16(f);
    return *reinterpret_cast<short*>(&h);
}

__device__ __forceinline__ float bf2f(short s) {
    return __uint_as_float(((unsigned int)(unsigned short)s) << 16);
}

__device__ __forceinline__ void cvt4(float4 v, short* dst) {
    __hip_bfloat162 p0 = __float22bfloat162_rn(make_float2(v.x, v.y));
    __hip_bfloat162 p1 = __float22bfloat162_rn(make_float2(v.z, v.w));
    uint2 u;
    u.x = *reinterpret_cast<unsigned int*>(&p0);
    u.y = *reinterpret_cast<unsigned int*>(&p1);
    *reinterpret_cast<uint2*>(dst) = u;  // dst 8B-aligned
}

// ---------------------------------------------------------------------------
// prep: transpose-convert W (fp32 [k][h]) -> wt bf16 [m][h][k]. 48 blocks.
// ---------------------------------------------------------------------------
__global__ __launch_bounds__(256) void prep_kernel(
    const float* __restrict__ Wq, const float* __restrict__ Wk,
    const float* __restrict__ Wv, short* __restrict__ wt)
{
    const int blk = blockIdx.x;
    const int tid = threadIdx.x;
    const int m = blk >> 4;
    const int ks = (blk & 15) << 6;
    const float* W = (m == 0) ? Wq : (m == 1) ? Wk : Wv;
    __shared__ float tile[64][68];
#pragma unroll
    for (int t = 0; t < 4; t++) {
        int fi = tid + t * 256;
        int k = fi >> 4, h4 = (fi & 15) << 2;
        *(float4*)&tile[k][h4] = *(const float4*)&W[(size_t)(ks + k) * H_DIM + h4];
    }
    __syncthreads();
    const int h = tid >> 2, seg = (tid & 3) << 4;
    __align__(16) short tmp[16];
#pragma unroll
    for (int kk = 0; kk < 16; kk++) tmp[kk] = f2bf(tile[seg + kk][h]);
    short* dst = wt + ((size_t)m * H_DIM + h) * D_DIM + ks + seg;
    *(bf16x8*)dst = *(bf16x8*)tmp;
    *(bf16x8*)(dst + 8) = *(bf16x8*)(tmp + 8);
}

// ---------------------------------------------------------------------------
// proj: grid 512 (32 rows each), block 256. q|k|v (192 cols) per row tile,
// double-buffered LDS (1 barrier/iter) + global->reg prefetch.
// Outputs: qb,kb bf16 [t][h]; vt bf16 [b][h][t].
// ---------------------------------------------------------------------------
__global__ __launch_bounds__(256) void proj_kernel(
    const float* __restrict__ x, const short* __restrict__ wt,
    short* __restrict__ qb, short* __restrict__ kb, short* __restrict__ vt)
{
    __shared__ short xs[2][32][72];
    __shared__ short wsb[2][192][72];
    __shared__ short ot[32][200];

    const int tid = threadIdx.x;
    const int wv = tid >> 6;
    const int lane = tid & 63;
    const int l15 = lane & 15;
    const int quad = lane >> 4;
    const int t0 = blockIdx.x * 32;
    const int r0 = (wv & 1) * 16;
    const int c0 = (wv >> 1) * 96;

    f32x4 acc[6];
#pragma unroll
    for (int c = 0; c < 6; c++) acc[c] = (f32x4){0.f, 0.f, 0.f, 0.f};

    float4 xr[2];
    bf16x8 wr[6];
    auto load_tile = [&](int k0) {
#pragma unroll
        for (int t = 0; t < 2; t++) {
            int fi = tid + t * 256;
            int r = fi >> 4, c4 = (fi & 15) << 2;
            xr[t] = *(const float4*)&x[(size_t)(t0 + r) * D_DIM + k0 + c4];
        }
#pragma unroll
        for (int t = 0; t < 6; t++) {
            int fi = tid + t * 256;
            int hh = fi >> 3, sg = (fi & 7) << 3;
            wr[t] = *(const bf16x8*)&wt[(size_t)hh * D_DIM + k0 + sg];
        }
    };
    auto store_tile = [&](int buf) {
#pragma unroll
        for (int t = 0; t < 2; t++) {
            int fi = tid + t * 256;
            int r = fi >> 4, c4 = (fi & 15) << 2;
            cvt4(xr[t], &xs[buf][r][c4]);
        }
#pragma unroll
        for (int t = 0; t < 6; t++) {
            int fi = tid + t * 256;
            int hh = fi >> 3, sg = (fi & 7) << 3;
            *(bf16x8*)&wsb[buf][hh][sg] = wr[t];
        }
    };

    load_tile(0);
    store_tile(0);
    __syncthreads();

    for (int it = 0; it < 16; ++it) {
        const int cur = it & 1;
        if (it < 15) load_tile((it + 1) * 64);
#pragma unroll
        for (int ks = 0; ks < 2; ks++) {
            bf16x8 xa = *(const bf16x8*)&xs[cur][r0 + l15][ks * 32 + quad * 8];
#pragma unroll
            for (int ct = 0; ct < 6; ct++) {
                bf16x8 wb = *(const bf16x8*)&wsb[cur][c0 + ct * 16 + l15][ks * 32 + quad * 8];
                acc[ct] = mfma16(xa, wb, acc[ct]);
            }
        }
        if (it < 15) store_tile(cur ^ 1);
        __syncthreads();
    }

    // epilogue: C-frags -> LDS bf16 tile
#pragma unroll
    for (int ct = 0; ct < 6; ct++)
#pragma unroll
        for (int r = 0; r < 4; r++)
            ot[r0 + quad * 4 + r][c0 + ct * 16 + l15] = f2bf(acc[ct][r]);
    __syncthreads();
#pragma unroll
    for (int t = 0; t < 2; t++) {
        int fi = tid + t * 256;
        int row = fi >> 4, sg = fi & 15;
        bf16x8 v = *(const bf16x8*)&ot[row][sg * 8];
        short* dst = (sg < 8)
            ? &qb[(size_t)(t0 + row) * H_DIM + sg * 8]
            : &kb[(size_t)(t0 + row) * H_DIM + (sg - 8) * 8];
        *(bf16x8*)dst = v;
    }
    {
        const int h = tid >> 2, ts = (tid & 3) << 3;
        const int bb = t0 >> 11;
        const int tloc = (t0 & 2047) + ts;
        __align__(16) short tmp[8];
#pragma unroll
        for (int i = 0; i < 8; i++) tmp[i] = ot[ts + i][128 + h];
        *(bf16x8*)&vt[((size_t)bb * H_DIM + h) * T_DIM + tloc] = *(bf16x8*)tmp;
    }
}

// ---------------------------------------------------------------------------
// stats: Z[k] = sum_{q>=k} exp(s*scale), then vt[:,k] *= 1/Z[k] in-place.
// grid (64, 8): block = k-strip pair {sa, 127-sa} (16 cols each, uniform
// 129 q-tiles combined); 4 waves split the q-range. K stationary in regs,
// Q streamed w/ ping-pong prefetch. No Zbuf — V pre-scaled for out.
// ---------------------------------------------------------------------------
__global__ __launch_bounds__(256) void stats_kernel(
    const short* __restrict__ qb, const short* __restrict__ kb,
    short* __restrict__ vt)
{
    __shared__ float zred[4][2][16];
    __shared__ float zfin[2][16];
    const int tid = threadIdx.x;
    const int wv = tid >> 6;
    const int lane = tid & 63;
    const int l15 = lane & 15;
    const int quad = lane >> 4;
    const int b = blockIdx.y;
    const int sa = blockIdx.x;       // 0..63
    const int sb = 127 - sa;
    const int Ta = 128 - sa;

    const short* qB_ = qb + (size_t)b * T_DIM * H_DIM;
    const short* kB_ = kb + (size_t)b * T_DIM * H_DIM;

    bf16x8 ka[2][2];
    {
        const short* kp = &kB_[(sa * 16 + l15) * H_DIM + quad * 8];
        ka[0][0] = *(const bf16x8*)kp;
        ka[0][1] = *(const bf16x8*)(kp + 32);
        const short* kp2 = &kB_[(sb * 16 + l15) * H_DIM + quad * 8];
        ka[1][0] = *(const bf16x8*)kp2;
        ka[1][1] = *(const bf16x8*)(kp2 + 32);
    }

    float acc[2][4];
#pragma unroll
    for (int s = 0; s < 2; s++)
#pragma unroll
        for (int r = 0; r < 4; r++) acc[s][r] = 0.f;

    const int v0 = (wv * 129) >> 2;
    const int v1 = ((wv + 1) * 129) >> 2;

#pragma unroll
    for (int seg = 0; seg < 2; ++seg) {
        const int strip = seg ? sb : sa;
        const int base = seg ? Ta : 0;
        const int lo = seg ? max(v0, Ta) : v0;
        const int hi = seg ? v1 : min(v1, Ta);
        const bf16x8 a0 = ka[seg][0], a1 = ka[seg][1];

        bf16x8 qA0, qA1, qB0, qB1;
        auto loadQ = [&](int v, bf16x8& r0, bf16x8& r1) {
            int qt = strip + (v - base);
            const short* qp = &qB_[(qt * 16 + l15) * H_DIM + quad * 8];
            r0 = *(const bf16x8*)qp;
            r1 = *(const bf16x8*)(qp + 32);
        };
        auto comp = [&](int v, bf16x8 b0, bf16x8 b1) {
            int qt = strip + (v - base);
            f32x4 s = mfma16(a0, b0, (f32x4){0.f, 0.f, 0.f, 0.f});
            s = mfma16(a1, b1, s);
            const bool diag = (qt == strip);
#pragma unroll
            for (int r = 0; r < 4; ++r) {
                float e = __expf(s[r] * SCALE);
                if (diag && (quad * 4 + r) > l15) e = 0.f;
                acc[seg][r] += e;
            }
        };

        int v = lo;
        if (v < hi) loadQ(v, qA0, qA1);
        while (v < hi) {
            if (v + 1 < hi) loadQ(v + 1, qB0, qB1);
            comp(v, qA0, qA1);
            ++v;
            if (v >= hi) break;
            if (v + 1 < hi) loadQ(v + 1, qA0, qA1);
            comp(v, qB0, qB1);
            ++v;
        }
    }

    // butterfly over l15 (sum across 16 q-cols), then LDS combine of 4 waves
#pragma unroll
    for (int seg = 0; seg < 2; ++seg)
#pragma unroll
        for (int r = 0; r < 4; ++r) {
            float z = acc[seg][r];
            z += __shfl_xor(z, 1);
            z += __shfl_xor(z, 2);
            z += __shfl_xor(z, 4);
            z += __shfl_xor(z, 8);
            acc[seg][r] = z;
        }
    if (l15 == 0) {
#pragma unroll
        for (int seg = 0; seg < 2; ++seg)
#pragma unroll
            for (int r = 0; r < 4; ++r)
                zred[wv][seg][quad * 4 + r] = acc[seg][r];
    }
    __syncthreads();
    if (tid < 32) {
        int seg = tid >> 4, col = tid & 15;
        float z = zred[0][seg][col] + zred[1][seg][col] +
                  zred[2][seg][col] + zred[3][seg][col];
        zfin[seg][col] = rcp_fast(z);
    }
    __syncthreads();

    // scale vt columns of both strips by 1/Z: 2 strips x 64 h x 16 t
    {
        const int seg = tid >> 7;             // 0/1
        const int rem = tid & 127;
        const int h = rem >> 1;               // 0..63
        const int c8 = (rem & 1) * 8;         // 0 or 8
        const int strip = seg ? sb : sa;
        short* vp = vt + ((size_t)b * H_DIM + h) * T_DIM + strip * 16 + c8;
        bf16x8 vv = *(bf16x8*)vp;
        __align__(16) short tmp[8];
#pragma unroll
        for (int i = 0; i < 8; i++)
            tmp[i] = f2bf(bf2f(vv[i]) * zfin[seg][c8 + i]);
        *(bf16x8*)vp = *(bf16x8*)tmp;
    }
}

// ---------------------------------------------------------------------------
// out: grid (64, 8), block 256. Block = strip pair {s, 127-s} (16 q-rows
// each, uniform work); waves quarter the k-range. Ping-pong register
// prefetch of K/V. V is pre-scaled by 1/Z, so P = exp(s*scale) directly.
// Partial O combined in LDS, coalesced stores.
// ---------------------------------------------------------------------------
__global__ __launch_bounds__(256) void out_kernel(
    const short* __restrict__ qb, const short* __restrict__ kb,
    const short* __restrict__ vt, float* __restrict__ out)
{
    __shared__ float osum[4][2][16][68];   // 34.8 KB
    __shared__ short pbuf[4][16][40];      // per-wave P tile

    const int tid = threadIdx.x;
    const int wv = tid >> 6;
    const int lane = tid & 63;
    const int l15 = lane & 15;
    const int quad = lane >> 4;
    const int b = blockIdx.y;
    const int sA = blockIdx.x;

    const short* qB_ = qb + (size_t)b * T_DIM * H_DIM;
    const short* kB_ = kb + (size_t)b * T_DIM * H_DIM;
    const short* vB_ = vt + (size_t)b * H_DIM * T_DIM;
    short* pb = &pbuf[wv][0][0];

#pragma unroll
    for (int half = 0; half < 2; half++) {
        const int s = half ? (127 - sA) : sA;
        const int q0 = s * 16;
        const int Ts = (s >> 1) + 1;
        const int lo = (wv * Ts) >> 2;
        const int hi = ((wv + 1) * Ts) >> 2;

        const bf16x8 qa0 = *(const bf16x8*)&qB_[(q0 + l15) * H_DIM + quad * 8];
        const bf16x8 qa1 = *(const bf16x8*)&qB_[(q0 + l15) * H_DIM + 32 + quad * 8];

        f32x4 o0 = {0.f,0.f,0.f,0.f}, o1 = {0.f,0.f,0.f,0.f};
        f32x4 o2 = {0.f,0.f,0.f,0.f}, o3 = {0.f,0.f,0.f,0.f};

        bf16x8 krA[4], vrA[4], krB[4], vrB[4];

        auto loadT = [&](int kt, bf16x8* kr, bf16x8* vr) {
            const short* kp = &kB_[(kt * 32 + l15) * H_DIM + quad * 8];
            kr[0] = *(const bf16x8*)kp;
            kr[1] = *(const bf16x8*)(kp + 32);
            kr[2] = *(const bf16x8*)(kp + 16 * H_DIM);
            kr[3] = *(const bf16x8*)(kp + 16 * H_DIM + 32);
            const short* vp = &vB_[(size_t)l15 * T_DIM + kt * 32 + quad * 8];
            vr[0] = *(const bf16x8*)vp;
            vr[1] = *(const bf16x8*)(vp + 16 * T_DIM);
            vr[2] = *(const bf16x8*)(vp + 32 * T_DIM);
            vr[3] = *(const bf16x8*)(vp + 48 * T_DIM);
        };
        auto compT = [&](int kt, bf16x8* kr, bf16x8* vr) {
            f32x4 z4 = {0.f,0.f,0.f,0.f};
            f32x4 s0 = mfma16(qa0, kr[0], z4);
            s0 = mfma16(qa1, kr[1], s0);
            f32x4 s1 = mfma16(qa0, kr[2], z4);
            s1 = mfma16(qa1, kr[3], s1);
            const bool fullT = (kt * 32 + 31) <= q0;
            const int kg0 = kt * 32 + l15;
            const int kg1 = kg0 + 16;
#pragma unroll
            for (int r = 0; r < 4; r++) {
                int qg = q0 + quad * 4 + r;
                float e0 = __expf(s0[r] * SCALE);
                float e1 = __expf(s1[r] * SCALE);
                if (!fullT) {
                    if (kg0 > qg) e0 = 0.f;
                    if (kg1 > qg) e1 = 0.f;
                }
                pb[(quad * 4 + r) * 40 + l15] = f2bf(e0);
                pb[(quad * 4 + r) * 40 + 16 + l15] = f2bf(e1);
            }
            __asm__ volatile("s_waitcnt lgkmcnt(0)" ::: "memory");
            bf16x8 pa = *(const bf16x8*)&pb[l15 * 40 + quad * 8];
            o0 = mfma16(pa, vr[0], o0);
            o1 = mfma16(pa, vr[1], o1);
            o2 = mfma16(pa, vr[2], o2);
            o3 = mfma16(pa, vr[3], o3);
        };

        int kt = lo;
        if (kt < hi) loadT(kt, krA, vrA);
        while (kt < hi) {
            if (kt + 1 < hi) loadT(kt + 1, krB, vrB);
            compT(kt, krA, vrA);
            ++kt;
            if (kt >= hi) break;
            if (kt + 1 < hi) loadT(kt + 1, krA, vrA);
            compT(kt, krB, vrB);
            ++kt;
        }

#pragma unroll
        for (int r = 0; r < 4; r++) {
            osum[wv][half][quad * 4 + r][l15]      = o0[r];
            osum[wv][half][quad * 4 + r][16 + l15] = o1[r];
            osum[wv][half][quad * 4 + r][32 + l15] = o2[r];
            osum[wv][half][quad * 4 + r][48 + l15] = o3[r];
        }
    }
    __syncthreads();

    const int half = tid >> 7;
    const int row = (tid >> 3) & 15;
    const int h0 = (tid & 7) * 8;
    const int s = half ? (127 - sA) : sA;
    float a[8];
#pragma unroll
    for (int i = 0; i < 8; i++) a[i] = 0.f;
#pragma unroll
    for (int w = 0; w < 4; w++)
#pragma unroll
        for (int i = 0; i < 8; i++) a[i] += osum[w][half][row][h0 + i];
    float* dst = &out[(size_t)(b * T_DIM + s * 16 + row) * H_DIM + h0];
    *(float4*)dst = make_float4(a[0], a[1], a[2], a[3]);
    *(float4*)(dst + 4) = make_float4(a[4], a[5], a[6], a[7]);
}

// ---------------------------------------------------------------------------
extern "C" void kernel_launch(void* const* d_in, const int* in_sizes, int n_in,
                              void* d_out, int out_size, void* d_ws, size_t ws_size,
                              hipStream_t stream) {
    const float* x  = (const float*)d_in[0];
    const float* Wk = (const float*)d_in[1];
    const float* Wq = (const float*)d_in[2];
    const float* Wv = (const float*)d_in[3];
    float* out = (float*)d_out;

    short* qbuf = (short*)d_ws;                       // 16384*64 bf16
    short* kbuf = qbuf + (size_t)16384 * 64;
    short* vtbuf = kbuf + (size_t)16384 * 64;         // [b][h][t]
    short* wtbuf = vtbuf + (size_t)16384 * 64;        // [3][64][1024]

    prep_kernel<<<48, 256, 0, stream>>>(Wq, Wk, Wv, wtbuf);
    proj_kernel<<<512, 256, 0, stream>>>(x, wtbuf, qbuf, kbuf, vtbuf);
    stats_kernel<<<dim3(64, B_DIM), 256, 0, stream>>>(qbuf, kbuf, vtbuf);
    out_kernel<<<dim3(64, B_DIM), 256, 0, stream>>>(qbuf, kbuf, vtbuf, out);
}

// Round 7
// 163.651 us; speedup vs baseline: 1.1706x; 1.0321x over previous
//
#include <hip/hip_runtime.h>
#include <hip/hip_bf16.h>
#include <math.h>

#define B_DIM 8
#define T_DIM 2048
#define D_DIM 1024
#define H_DIM 64
#define SCALE 0.125f

typedef __attribute__((ext_vector_type(8))) short bf16x8;
typedef __attribute__((ext_vector_type(4))) float f32x4;

__device__ __forceinline__ f32x4 mfma16(bf16x8 a, bf16x8 b, f32x4 c) {
    return __builtin_amdgcn_mfma_f32_16x16x32_bf16(a, b, c, 0, 0, 0);
}

__device__ __forceinline__ float rcp_fast(float x) {
    float r;
    asm volatile("v_rcp_f32 %0, %1" : "=v"(r) : "v"(x));
    return r;
}

__device__ __forceinline__ short f2bf(float f) {
    __hip_bfloat16 h = __float2bfloat16(f);
    return *reinterpret_cast<short*>(&h);
}

__device__ __forceinline__ float bf2f(short s) {
    return __uint_as_float(((unsigned int)(unsigned short)s) << 16);
}

__device__ __forceinline__ void cvt4(float4 v, short* dst) {
    __hip_bfloat162 p0 = __float22bfloat162_rn(make_float2(v.x, v.y));
    __hip_bfloat162 p1 = __float22bfloat162_rn(make_float2(v.z, v.w));
    uint2 u;
    u.x = *reinterpret_cast<unsigned int*>(&p0);
    u.y = *reinterpret_cast<unsigned int*>(&p1);
    *reinterpret_cast<uint2*>(dst) = u;  // dst 8B-aligned
}

// ---------------------------------------------------------------------------
// prep: transpose-convert W (fp32 [k][h]) -> wt bf16 [m][h][k]. 48 blocks.
// ---------------------------------------------------------------------------
__global__ __launch_bounds__(256) void prep_kernel(
    const float* __restrict__ Wq, const float* __restrict__ Wk,
    const float* __restrict__ Wv, short* __restrict__ wt)
{
    const int blk = blockIdx.x;
    const int tid = threadIdx.x;
    const int m = blk >> 4;
    const int ks = (blk & 15) << 6;
    const float* W = (m == 0) ? Wq : (m == 1) ? Wk : Wv;
    __shared__ float tile[64][68];
#pragma unroll
    for (int t = 0; t < 4; t++) {
        int fi = tid + t * 256;
        int k = fi >> 4, h4 = (fi & 15) << 2;
        *(float4*)&tile[k][h4] = *(const float4*)&W[(size_t)(ks + k) * H_DIM + h4];
    }
    __syncthreads();
    const int h = tid >> 2, seg = (tid & 3) << 4;
    __align__(16) short tmp[16];
#pragma unroll
    for (int kk = 0; kk < 16; kk++) tmp[kk] = f2bf(tile[seg + kk][h]);
    short* dst = wt + ((size_t)m * H_DIM + h) * D_DIM + ks + seg;
    *(bf16x8*)dst = *(bf16x8*)tmp;
    *(bf16x8*)(dst + 8) = *(bf16x8*)(tmp + 8);
}

// ---------------------------------------------------------------------------
// proj: grid 512 (32 rows each), block 256. q|k|v (192 cols) per row tile,
// double-buffered LDS (1 barrier/iter) + global->reg prefetch.
// Outputs: qb,kb bf16 [t][h]; vt bf16 [b][h][t].
// ---------------------------------------------------------------------------
__global__ __launch_bounds__(256) void proj_kernel(
    const float* __restrict__ x, const short* __restrict__ wt,
    short* __restrict__ qb, short* __restrict__ kb, short* __restrict__ vt)
{
    __shared__ short xs[2][32][72];
    __shared__ short wsb[2][192][72];
    __shared__ short ot[32][200];

    const int tid = threadIdx.x;
    const int wv = tid >> 6;
    const int lane = tid & 63;
    const int l15 = lane & 15;
    const int quad = lane >> 4;
    const int t0 = blockIdx.x * 32;
    const int r0 = (wv & 1) * 16;
    const int c0 = (wv >> 1) * 96;

    f32x4 acc[6];
#pragma unroll
    for (int c = 0; c < 6; c++) acc[c] = (f32x4){0.f, 0.f, 0.f, 0.f};

    float4 xr[2];
    bf16x8 wr[6];
    auto load_tile = [&](int k0) {
#pragma unroll
        for (int t = 0; t < 2; t++) {
            int fi = tid + t * 256;
            int r = fi >> 4, c4 = (fi & 15) << 2;
            xr[t] = *(const float4*)&x[(size_t)(t0 + r) * D_DIM + k0 + c4];
        }
#pragma unroll
        for (int t = 0; t < 6; t++) {
            int fi = tid + t * 256;
            int hh = fi >> 3, sg = (fi & 7) << 3;
            wr[t] = *(const bf16x8*)&wt[(size_t)hh * D_DIM + k0 + sg];
        }
    };
    auto store_tile = [&](int buf) {
#pragma unroll
        for (int t = 0; t < 2; t++) {
            int fi = tid + t * 256;
            int r = fi >> 4, c4 = (fi & 15) << 2;
            cvt4(xr[t], &xs[buf][r][c4]);
        }
#pragma unroll
        for (int t = 0; t < 6; t++) {
            int fi = tid + t * 256;
            int hh = fi >> 3, sg = (fi & 7) << 3;
            *(bf16x8*)&wsb[buf][hh][sg] = wr[t];
        }
    };

    load_tile(0);
    store_tile(0);
    __syncthreads();

    for (int it = 0; it < 16; ++it) {
        const int cur = it & 1;
        if (it < 15) load_tile((it + 1) * 64);
#pragma unroll
        for (int ks = 0; ks < 2; ks++) {
            bf16x8 xa = *(const bf16x8*)&xs[cur][r0 + l15][ks * 32 + quad * 8];
#pragma unroll
            for (int ct = 0; ct < 6; ct++) {
                bf16x8 wb = *(const bf16x8*)&wsb[cur][c0 + ct * 16 + l15][ks * 32 + quad * 8];
                acc[ct] = mfma16(xa, wb, acc[ct]);
            }
        }
        if (it < 15) store_tile(cur ^ 1);
        __syncthreads();
    }

    // epilogue: C-frags -> LDS bf16 tile
#pragma unroll
    for (int ct = 0; ct < 6; ct++)
#pragma unroll
        for (int r = 0; r < 4; r++)
            ot[r0 + quad * 4 + r][c0 + ct * 16 + l15] = f2bf(acc[ct][r]);
    __syncthreads();
#pragma unroll
    for (int t = 0; t < 2; t++) {
        int fi = tid + t * 256;
        int row = fi >> 4, sg = fi & 15;
        bf16x8 v = *(const bf16x8*)&ot[row][sg * 8];
        short* dst = (sg < 8)
            ? &qb[(size_t)(t0 + row) * H_DIM + sg * 8]
            : &kb[(size_t)(t0 + row) * H_DIM + (sg - 8) * 8];
        *(bf16x8*)dst = v;
    }
    {
        const int h = tid >> 2, ts = (tid & 3) << 3;
        const int bb = t0 >> 11;
        const int tloc = (t0 & 2047) + ts;
        __align__(16) short tmp[8];
#pragma unroll
        for (int i = 0; i < 8; i++) tmp[i] = ot[ts + i][128 + h];
        *(bf16x8*)&vt[((size_t)bb * H_DIM + h) * T_DIM + tloc] = *(bf16x8*)tmp;
    }
}

// ---------------------------------------------------------------------------
// stats: Z[k] = sum_{q>=k} exp(s*scale), then vt[:,k] *= 1/Z[k] in-place.
// grid 512 (1-D): batch = bx & 7 so all blocks of a batch share an XCD
// (round-robin linear-ID mapping) -> K/Q stay in that XCD's 4 MB L2.
// Block = k-strip pair {sa, 127-sa}; K stationary, Q ping-pong prefetch.
// ---------------------------------------------------------------------------
__global__ __launch_bounds__(256) void stats_kernel(
    const short* __restrict__ qb, const short* __restrict__ kb,
    short* __restrict__ vt)
{
    __shared__ float zred[4][2][16];
    __shared__ float zfin[2][16];
    const int tid = threadIdx.x;
    const int wv = tid >> 6;
    const int lane = tid & 63;
    const int l15 = lane & 15;
    const int quad = lane >> 4;
    const int b = blockIdx.x & 7;          // XCD-pinned batch
    const int sa = blockIdx.x >> 3;        // 0..63
    const int sb = 127 - sa;
    const int Ta = 128 - sa;

    const short* qB_ = qb + (size_t)b * T_DIM * H_DIM;
    const short* kB_ = kb + (size_t)b * T_DIM * H_DIM;

    bf16x8 ka[2][2];
    {
        const short* kp = &kB_[(sa * 16 + l15) * H_DIM + quad * 8];
        ka[0][0] = *(const bf16x8*)kp;
        ka[0][1] = *(const bf16x8*)(kp + 32);
        const short* kp2 = &kB_[(sb * 16 + l15) * H_DIM + quad * 8];
        ka[1][0] = *(const bf16x8*)kp2;
        ka[1][1] = *(const bf16x8*)(kp2 + 32);
    }

    float acc[2][4];
#pragma unroll
    for (int s = 0; s < 2; s++)
#pragma unroll
        for (int r = 0; r < 4; r++) acc[s][r] = 0.f;

    const int v0 = (wv * 129) >> 2;
    const int v1 = ((wv + 1) * 129) >> 2;

#pragma unroll
    for (int seg = 0; seg < 2; ++seg) {
        const int strip = seg ? sb : sa;
        const int base = seg ? Ta : 0;
        const int lo = seg ? max(v0, Ta) : v0;
        const int hi = seg ? v1 : min(v1, Ta);
        const bf16x8 a0 = ka[seg][0], a1 = ka[seg][1];

        bf16x8 qA0, qA1, qB0, qB1;
        auto loadQ = [&](int v, bf16x8& r0, bf16x8& r1) {
            int qt = strip + (v - base);
            const short* qp = &qB_[(qt * 16 + l15) * H_DIM + quad * 8];
            r0 = *(const bf16x8*)qp;
            r1 = *(const bf16x8*)(qp + 32);
        };
        auto comp = [&](int v, bf16x8 b0, bf16x8 b1) {
            int qt = strip + (v - base);
            f32x4 s = mfma16(a0, b0, (f32x4){0.f, 0.f, 0.f, 0.f});
            s = mfma16(a1, b1, s);
            const bool diag = (qt == strip);
#pragma unroll
            for (int r = 0; r < 4; ++r) {
                float e = __expf(s[r] * SCALE);
                if (diag && (quad * 4 + r) > l15) e = 0.f;
                acc[seg][r] += e;
            }
        };

        int v = lo;
        if (v < hi) loadQ(v, qA0, qA1);
        while (v < hi) {
            if (v + 1 < hi) loadQ(v + 1, qB0, qB1);
            comp(v, qA0, qA1);
            ++v;
            if (v >= hi) break;
            if (v + 1 < hi) loadQ(v + 1, qA0, qA1);
            comp(v, qB0, qB1);
            ++v;
        }
    }

    // butterfly over l15 (sum across 16 q-cols), then LDS combine of 4 waves
#pragma unroll
    for (int seg = 0; seg < 2; ++seg)
#pragma unroll
        for (int r = 0; r < 4; ++r) {
            float z = acc[seg][r];
            z += __shfl_xor(z, 1);
            z += __shfl_xor(z, 2);
            z += __shfl_xor(z, 4);
            z += __shfl_xor(z, 8);
            acc[seg][r] = z;
        }
    if (l15 == 0) {
#pragma unroll
        for (int seg = 0; seg < 2; ++seg)
#pragma unroll
            for (int r = 0; r < 4; ++r)
                zred[wv][seg][quad * 4 + r] = acc[seg][r];
    }
    __syncthreads();
    if (tid < 32) {
        int seg = tid >> 4, col = tid & 15;
        float z = zred[0][seg][col] + zred[1][seg][col] +
                  zred[2][seg][col] + zred[3][seg][col];
        zfin[seg][col] = rcp_fast(z);
    }
    __syncthreads();

    // scale vt columns of both strips by 1/Z: 2 strips x 64 h x 16 t
    {
        const int seg = tid >> 7;             // 0/1
        const int rem = tid & 127;
        const int h = rem >> 1;               // 0..63
        const int c8 = (rem & 1) * 8;         // 0 or 8
        const int strip = seg ? sb : sa;
        short* vp = vt + ((size_t)b * H_DIM + h) * T_DIM + strip * 16 + c8;
        bf16x8 vv = *(bf16x8*)vp;
        __align__(16) short tmp[8];
#pragma unroll
        for (int i = 0; i < 8; i++)
            tmp[i] = f2bf(bf2f(vv[i]) * zfin[seg][c8 + i]);
        *(bf16x8*)vp = *(bf16x8*)tmp;
    }
}

// ---------------------------------------------------------------------------
// out: grid 512 (1-D): batch = bx & 7 (XCD-pinned -> K/V L2-resident).
// Block = strip pair {s, 127-s} (16 q-rows each, uniform work); waves
// quarter the k-range. Ping-pong register prefetch of K/V. V pre-scaled by
// 1/Z, so P = exp(s*scale) directly. Partial O combined in LDS.
// ---------------------------------------------------------------------------
__global__ __launch_bounds__(256) void out_kernel(
    const short* __restrict__ qb, const short* __restrict__ kb,
    const short* __restrict__ vt, float* __restrict__ out)
{
    __shared__ float osum[4][2][16][68];   // 34.8 KB
    __shared__ short pbuf[4][16][40];      // per-wave P tile

    const int tid = threadIdx.x;
    const int wv = tid >> 6;
    const int lane = tid & 63;
    const int l15 = lane & 15;
    const int quad = lane >> 4;
    const int b = blockIdx.x & 7;          // XCD-pinned batch
    const int sA = blockIdx.x >> 3;        // 0..63

    const short* qB_ = qb + (size_t)b * T_DIM * H_DIM;
    const short* kB_ = kb + (size_t)b * T_DIM * H_DIM;
    const short* vB_ = vt + (size_t)b * H_DIM * T_DIM;
    short* pb = &pbuf[wv][0][0];

#pragma unroll
    for (int half = 0; half < 2; half++) {
        const int s = half ? (127 - sA) : sA;
        const int q0 = s * 16;
        const int Ts = (s >> 1) + 1;
        const int lo = (wv * Ts) >> 2;
        const int hi = ((wv + 1) * Ts) >> 2;

        const bf16x8 qa0 = *(const bf16x8*)&qB_[(q0 + l15) * H_DIM + quad * 8];
        const bf16x8 qa1 = *(const bf16x8*)&qB_[(q0 + l15) * H_DIM + 32 + quad * 8];

        f32x4 o0 = {0.f,0.f,0.f,0.f}, o1 = {0.f,0.f,0.f,0.f};
        f32x4 o2 = {0.f,0.f,0.f,0.f}, o3 = {0.f,0.f,0.f,0.f};

        bf16x8 krA[4], vrA[4], krB[4], vrB[4];

        auto loadT = [&](int kt, bf16x8* kr, bf16x8* vr) {
            const short* kp = &kB_[(kt * 32 + l15) * H_DIM + quad * 8];
            kr[0] = *(const bf16x8*)kp;
            kr[1] = *(const bf16x8*)(kp + 32);
            kr[2] = *(const bf16x8*)(kp + 16 * H_DIM);
            kr[3] = *(const bf16x8*)(kp + 16 * H_DIM + 32);
            const short* vp = &vB_[(size_t)l15 * T_DIM + kt * 32 + quad * 8];
            vr[0] = *(const bf16x8*)vp;
            vr[1] = *(const bf16x8*)(vp + 16 * T_DIM);
            vr[2] = *(const bf16x8*)(vp + 32 * T_DIM);
            vr[3] = *(const bf16x8*)(vp + 48 * T_DIM);
        };
        auto compT = [&](int kt, bf16x8* kr, bf16x8* vr) {
            f32x4 z4 = {0.f,0.f,0.f,0.f};
            f32x4 s0 = mfma16(qa0, kr[0], z4);
            s0 = mfma16(qa1, kr[1], s0);
            f32x4 s1 = mfma16(qa0, kr[2], z4);
            s1 = mfma16(qa1, kr[3], s1);
            const bool fullT = (kt * 32 + 31) <= q0;
            const int kg0 = kt * 32 + l15;
            const int kg1 = kg0 + 16;
#pragma unroll
            for (int r = 0; r < 4; r++) {
                int qg = q0 + quad * 4 + r;
                float e0 = __expf(s0[r] * SCALE);
                float e1 = __expf(s1[r] * SCALE);
                if (!fullT) {
                    if (kg0 > qg) e0 = 0.f;
                    if (kg1 > qg) e1 = 0.f;
                }
                pb[(quad * 4 + r) * 40 + l15] = f2bf(e0);
                pb[(quad * 4 + r) * 40 + 16 + l15] = f2bf(e1);
            }
            __asm__ volatile("s_waitcnt lgkmcnt(0)" ::: "memory");
            bf16x8 pa = *(const bf16x8*)&pb[l15 * 40 + quad * 8];
            o0 = mfma16(pa, vr[0], o0);
            o1 = mfma16(pa, vr[1], o1);
            o2 = mfma16(pa, vr[2], o2);
            o3 = mfma16(pa, vr[3], o3);
        };

        int kt = lo;
        if (kt < hi) loadT(kt, krA, vrA);
        while (kt < hi) {
            if (kt + 1 < hi) loadT(kt + 1, krB, vrB);
            compT(kt, krA, vrA);
            ++kt;
            if (kt >= hi) break;
            if (kt + 1 < hi) loadT(kt + 1, krA, vrA);
            compT(kt, krB, vrB);
            ++kt;
        }

#pragma unroll
        for (int r = 0; r < 4; r++) {
            osum[wv][half][quad * 4 + r][l15]      = o0[r];
            osum[wv][half][quad * 4 + r][16 + l15] = o1[r];
            osum[wv][half][quad * 4 + r][32 + l15] = o2[r];
            osum[wv][half][quad * 4 + r][48 + l15] = o3[r];
        }
    }
    __syncthreads();

    const int half = tid >> 7;
    const int row = (tid >> 3) & 15;
    const int h0 = (tid & 7) * 8;
    const int s = half ? (127 - sA) : sA;
    float a[8];
#pragma unroll
    for (int i = 0; i < 8; i++) a[i] = 0.f;
#pragma unroll
    for (int w = 0; w < 4; w++)
#pragma unroll
        for (int i = 0; i < 8; i++) a[i] += osum[w][half][row][h0 + i];
    float* dst = &out[(size_t)(b * T_DIM + s * 16 + row) * H_DIM + h0];
    *(float4*)dst = make_float4(a[0], a[1], a[2], a[3]);
    *(float4*)(dst + 4) = make_float4(a[4], a[5], a[6], a[7]);
}

// ---------------------------------------------------------------------------
extern "C" void kernel_launch(void* const* d_in, const int* in_sizes, int n_in,
                              void* d_out, int out_size, void* d_ws, size_t ws_size,
                              hipStream_t stream) {
    const float* x  = (const float*)d_in[0];
    const float* Wk = (const float*)d_in[1];
    const float* Wq = (const float*)d_in[2];
    const float* Wv = (const float*)d_in[3];
    float* out = (float*)d_out;

    short* qbuf = (short*)d_ws;                       // 16384*64 bf16
    short* kbuf = qbuf + (size_t)16384 * 64;
    short* vtbuf = kbuf + (size_t)16384 * 64;         // [b][h][t]
    short* wtbuf = vtbuf + (size_t)16384 * 64;        // [3][64][1024]

    prep_kernel<<<48, 256, 0, stream>>>(Wq, Wk, Wv, wtbuf);
    proj_kernel<<<512, 256, 0, stream>>>(x, wtbuf, qbuf, kbuf, vtbuf);
    stats_kernel<<<512, 256, 0, stream>>>(qbuf, kbuf, vtbuf);
    out_kernel<<<512, 256, 0, stream>>>(qbuf, kbuf, vtbuf, out);
}